// Round 7
// baseline (236.959 us; speedup 1.0000x reference)
//
#include <hip/hip_runtime.h>
#include <hip/hip_bf16.h>

// 9x9 VALID conv, 4096x4096 f32 -> 4088x4088 f32, + scalar bias.
// No-LDS, 4x4 micro-tile, 12-row sliding window with double-buffered
// one-row-ahead prefetch (parity-static under full unroll -> consume is
// register renaming, zero copies). Taps uniform -> SGPR.
//
// Launch-bounds history: (256,4) capped RA at 64 VGPR -> 1.9GB spill
// (r4/r5). No clause -> RA took 164 VGPR, occupancy 10.7% (r6).
// (256,2) empirically caps at 128 with no spill (r2): min live set here
// is ~70 regs, so 128 cap = 4 waves/SIMD guaranteed, no spill possible.

#define H 4096
#define W 4096
#define OH 4088
#define OW 4088

__global__ __launch_bounds__(256, 2)
void conv9x9_kernel(const float* __restrict__ X,
                    const float* __restrict__ K,
                    const float* __restrict__ B,
                    float* __restrict__ out) {
    const int tid = threadIdx.x;
    const int tx = tid & 63;        // 64 lanes across columns (4 cols each)
    const int ty = tid >> 6;        // 4 waves stacked vertically (4 rows each)
    const int bx = blockIdx.x;      // 16 col-tiles of 256
    const int by = blockIdx.y;      // 256 row-tiles of 16

    const int r0 = by * 16 + ty * 4;    // first output row of this thread
    const int c0 = bx * 256 + tx * 4;   // first output col of this thread

    // clamped float4 column bases (identity for lanes whose outputs are live;
    // clamped lanes only produce outputs masked at store time)
    int gc[3];
#pragma unroll
    for (int q = 0; q < 3; ++q) {
        int g = c0 + 4 * q;
        gc[q] = (g > W - 4) ? (W - 4) : g;
    }

    const float bias = B[0];
    float acc[4][4];
#pragma unroll
    for (int i = 0; i < 4; ++i)
#pragma unroll
        for (int j = 0; j < 4; ++j)
            acc[i][j] = bias;

#define LOADROW(buf, t_) {                                        \
        int gr = r0 + (t_); if (gr > H - 1) gr = H - 1;           \
        const float* rp = X + (size_t)gr * W;                     \
        buf[0] = *(const float4*)(rp + gc[0]);                    \
        buf[1] = *(const float4*)(rp + gc[1]);                    \
        buf[2] = *(const float4*)(rp + gc[2]); }

#define UNPACK(seg, buf)                                          \
        _Pragma("unroll")                                         \
        for (int q = 0; q < 3; ++q) {                             \
            seg[q * 4 + 0] = buf[q].x; seg[q * 4 + 1] = buf[q].y; \
            seg[q * 4 + 2] = buf[q].z; seg[q * 4 + 3] = buf[q].w; }

    float4 bufA[3], bufB[3];
    LOADROW(bufA, 0);   // r0 <= 4092 < H: no clamp actually taken

#pragma unroll
    for (int t = 0; t < 12; ++t) {
        float seg[12];
        // consume current buffer (renames: buffer is dead right after),
        // then issue next row's loads into the other buffer
        if ((t & 1) == 0) {
            UNPACK(seg, bufA);
            if (t < 11) LOADROW(bufB, t + 1);
        } else {
            UNPACK(seg, bufB);
            if (t < 11) LOADROW(bufA, t + 1);
        }

        // input row t contributes to output rows i = t-kr, kr in [0,8]
#pragma unroll
        for (int kr = 0; kr < 9; ++kr) {
            const int i = t - kr;
            if (i < 0 || i > 3) continue;    // compile-time pruned
#pragma unroll
            for (int kc = 0; kc < 9; ++kc) {
                const float kv = K[kr * 9 + kc];   // uniform -> SGPR
#pragma unroll
                for (int j = 0; j < 4; ++j)
                    acc[i][j] = fmaf(kv, seg[kc + j], acc[i][j]);
            }
        }
    }

    // store: per wave-row 64 lanes x float4 = 1KB contiguous.
    // c0 % 4 == 0 and OW % 4 == 0 -> a float4 is fully in or fully out.
    if (c0 < OW) {
#pragma unroll
        for (int i = 0; i < 4; ++i) {
            const int orow = r0 + i;
            if (orow < OH) {
                float4 v = { acc[i][0], acc[i][1], acc[i][2], acc[i][3] };
                *(float4*)(out + (size_t)orow * OW + c0) = v;
            }
        }
    }
}

extern "C" void kernel_launch(void* const* d_in, const int* in_sizes, int n_in,
                              void* d_out, int out_size, void* d_ws, size_t ws_size,
                              hipStream_t stream) {
    const float* X = (const float*)d_in[0];
    const float* K = (const float*)d_in[1];
    const float* B = (const float*)d_in[2];
    float* out = (float*)d_out;

    dim3 grid(W / 256, (OH + 15) / 16);   // 16 x 256 = 4096 blocks
    dim3 block(256);
    conv9x9_kernel<<<grid, block, 0, stream>>>(X, K, B, out);
}